// Round 14
// baseline (361.817 us; speedup 1.0000x reference)
//
#include <hip/hip_runtime.h>
#include <hip/hip_bf16.h>
#include <stdint.h>

#define NTOK 4096      // B*S
#define DIM  1024      // D
#define FF   4096      // F
#define NE   8         // experts
#define NPAIR (NTOK*2) // top-2

using short8 = __attribute__((ext_vector_type(8))) short;
using f32x4  = __attribute__((ext_vector_type(4))) float;
typedef unsigned short u16;
typedef unsigned int   u32;

#define GLD_LDS(gp, lp) \
  __builtin_amdgcn_global_load_lds((const __attribute__((address_space(1))) void*)(gp), \
                                   (__attribute__((address_space(3))) void*)(lp), 16, 0, 0)

__device__ __forceinline__ u16 f2bf(float f) {
  union { float f; u32 u; } v; v.f = f;
  u32 r = (v.u + 0x7fffu + ((v.u >> 16) & 1u)) >> 16;
  return (u16)r;
}
__device__ __forceinline__ float bf2f(u16 u) {
  union { u32 u; float f; } v; v.u = (u32)u << 16; return v.f;
}
__device__ __forceinline__ u32 pack2(float lo, float hi) {
  return (u32)f2bf(lo) | ((u32)f2bf(hi) << 16);
}
// exact rewrite of tanh-gelu: 0.5x(1+tanh(z)) == x * sigmoid(2z)
__device__ __forceinline__ float gelu_fast(float x) {
  float t = x * (-1.5957691216057308f - 0.07135481627822202f * x * x); // -2z
  return x / (1.0f + __expf(t));
}

// ---------------- weight conversions f32 -> bf16 (relayout per-expert) ----------------
__global__ __launch_bounds__(256) void cvt_w1_kernel(const float* __restrict__ w1, u16* __restrict__ w1b) {
  // in: [F][E][D]  ->  out: [E][F][D]
  size_t i4 = (size_t)blockIdx.x * 256 + threadIdx.x;
  int d4 = (int)(i4 & (DIM/4 - 1));
  size_t t = i4 >> 8;
  int f = (int)(t & (FF - 1));
  int e = (int)(t >> 12);
  float4 v = *(const float4*)(w1 + ((size_t)f * NE + e) * DIM + (size_t)d4 * 4);
  *(uint2*)(w1b + ((size_t)e * FF + f) * DIM + (size_t)d4 * 4) =
      make_uint2(pack2(v.x, v.y), pack2(v.z, v.w));
}

__global__ __launch_bounds__(256) void cvt_w2_kernel(const float* __restrict__ w2, u16* __restrict__ w2b) {
  // in: [D][E][F]  ->  out: [E][D][F]
  size_t i4 = (size_t)blockIdx.x * 256 + threadIdx.x;
  int f4 = (int)(i4 & (FF/4 - 1));
  size_t t = i4 >> 10;
  int d = (int)(t & (DIM - 1));
  int e = (int)(t >> 10);
  float4 v = *(const float4*)(w2 + ((size_t)d * NE + e) * FF + (size_t)f4 * 4);
  *(uint2*)(w2b + ((size_t)e * DIM + d) * FF + (size_t)f4 * 4) =
      make_uint2(pack2(v.x, v.y), pack2(v.z, v.w));
}

// ---------------- gating (fused with x -> bf16 cast); NO global atomics ----------------
__global__ __launch_bounds__(256) void gate_kernel(const float* __restrict__ x, const float* __restrict__ gw,
                                                   u16* __restrict__ xb,
                                                   int* __restrict__ tk_e, float* __restrict__ tk_p) {
  int tok  = blockIdx.x * 4 + (threadIdx.x >> 6);
  int lane = threadIdx.x & 63;
  const float* xr = x + (size_t)tok * DIM;
  u16* xw = xb + (size_t)tok * DIM;
  float acc[NE];
#pragma unroll
  for (int e = 0; e < NE; ++e) acc[e] = 0.f;
#pragma unroll
  for (int it = 0; it < 4; ++it) {
    int d = it * 256 + lane * 4;
    float4 xv = *(const float4*)(xr + d);
    *(uint2*)(xw + d) = make_uint2(pack2(xv.x, xv.y), pack2(xv.z, xv.w));
#pragma unroll
    for (int e = 0; e < NE; ++e) {
      float4 gv = *(const float4*)(gw + (size_t)e * DIM + d);
      acc[e] += xv.x * gv.x + xv.y * gv.y + xv.z * gv.z + xv.w * gv.w;
    }
  }
#pragma unroll
  for (int e = 0; e < NE; ++e)
#pragma unroll
    for (int off = 32; off; off >>= 1) acc[e] += __shfl_xor(acc[e], off);

  if (lane == 0) {
    float mx = acc[0];
#pragma unroll
    for (int e = 1; e < NE; ++e) mx = fmaxf(mx, acc[e]);
    float pr[NE]; float s = 0.f;
#pragma unroll
    for (int e = 0; e < NE; ++e) { pr[e] = __expf(acc[e] - mx); s += pr[e]; }
    float inv = 1.f / s;
    int e0 = 0; float p0 = pr[0];
#pragma unroll
    for (int e = 1; e < NE; ++e) if (pr[e] > p0) { p0 = pr[e]; e0 = e; }
    int e1 = (e0 == 0) ? 1 : 0; float p1 = pr[e1];
#pragma unroll
    for (int e = 0; e < NE; ++e) if (e != e0 && pr[e] > p1) { p1 = pr[e]; e1 = e; }
    tk_e[tok * 2]     = e0; tk_p[tok * 2]     = p0 * inv;
    tk_e[tok * 2 + 1] = e1; tk_p[tok * 2 + 1] = p1 * inv;
  }
}

// ---------------- routing: LDS histogram, 8 global atomics per block (G12) ----------------
__global__ __launch_bounds__(256) void route_count_kernel(const int* __restrict__ tk_e,
                                                          int* __restrict__ counts,
                                                          int* __restrict__ bbase,
                                                          int* __restrict__ pos_buf) {
  __shared__ int hist[NE];
  if (threadIdx.x < NE) hist[threadIdx.x] = 0;
  __syncthreads();
  int i = blockIdx.x * 256 + threadIdx.x;
  int e = tk_e[i];
  pos_buf[i] = atomicAdd(&hist[e], 1);
  __syncthreads();
  if (threadIdx.x < NE) {
    int c = hist[threadIdx.x];
    bbase[blockIdx.x * NE + threadIdx.x] = atomicAdd(&counts[threadIdx.x], c);
  }
}

__global__ void route_offsets_kernel(const int* __restrict__ counts, int* __restrict__ offsets) {
  if (threadIdx.x == 0) { int s = 0; for (int e = 0; e < NE; ++e) { offsets[e] = s; s += counts[e]; } }
}

__global__ __launch_bounds__(256) void scatter_kernel(const int* __restrict__ tk_e, const float* __restrict__ tk_p,
                                                      const int* __restrict__ offsets,
                                                      const int* __restrict__ bbase, const int* __restrict__ pos_buf,
                                                      int* __restrict__ pair_tok, float* __restrict__ pair_p,
                                                      int* __restrict__ inv_slot) {
  int i = blockIdx.x * 256 + threadIdx.x;
  int e = tk_e[i];
  int slot = offsets[e] + bbase[blockIdx.x * NE + e] + pos_buf[i];
  pair_tok[slot] = i >> 1;
  pair_p[slot]   = tk_p[i];
  inv_slot[i]    = slot;
}

// ---------------- grouped GEMM1: h[slot] = gelu(x[tok(slot)] @ w1_e^T + b1_e) ----------------
// R13 config (128x128, BK=32, gld_lds, dbuf 32KB, 2-phase, balanced XCD deal).
__global__ __launch_bounds__(256, 4) void gemm1_kernel(const u16* __restrict__ xb, const u16* __restrict__ w1b,
                                                       const float* __restrict__ b1g,
                                                       const int* __restrict__ pair_tok,
                                                       const int* __restrict__ offsets, const int* __restrict__ counts,
                                                       u16* __restrict__ h) {
  int c = blockIdx.x & 7;          // XCD (dispatch round-robin)
  int idx = blockIdx.x >> 3;       // 0..1023 within XCD
  int trow = idx & 31;
  int g = (idx >> 5) * 8 + c;      // panel-group 0..255, balanced across XCDs
  int e = g >> 5;
  int fblk = (g & 31) << 7;
  int M = counts[e];
  if (trow * 128 >= M) return;
  int off = offsets[e];

  __shared__ __align__(16) u16 sA[2][128 * 32];
  __shared__ __align__(16) u16 sB[2][128 * 32];

  int tid = threadIdx.x, lane = tid & 63, w = tid >> 6;
  int wr = w >> 1, wc = w & 1;

  int lr = lane >> 2;
  int cs = (lane & 3) ^ (((lane >> 2) ^ (lane >> 4)) & 3);
  const u16* gA[2]; const u16* gB[2];
#pragma unroll
  for (int cc = 0; cc < 2; ++cc) {
    int lrow = cc * 64 + w * 16 + lr;
    int arow = trow * 128 + lrow;
    int tok = pair_tok[off + (arow < M ? arow : M - 1)];
    gA[cc] = xb + (size_t)tok * DIM + cs * 8;
    gB[cc] = w1b + ((size_t)e * FF + fblk + lrow) * DIM + cs * 8;
  }

  f32x4 acc[4][4];
#pragma unroll
  for (int i = 0; i < 4; ++i)
#pragma unroll
    for (int j = 0; j < 4; ++j)
#pragma unroll
      for (int k = 0; k < 4; ++k) acc[i][j][k] = 0.f;

#define STAGE1(kt, b)                                                   \
  _Pragma("unroll")                                                     \
  for (int cc = 0; cc < 2; ++cc) {                                      \
    GLD_LDS(gA[cc] + (kt) * 32, &sA[b][(cc * 64 + w * 16) * 32]);       \
    GLD_LDS(gB[cc] + (kt) * 32, &sB[b][(cc * 64 + w * 16) * 32]);       \
  }

  int frow = lane & 15, kq = lane >> 4;
  int sl = kq ^ ((frow ^ (frow >> 2)) & 3);

#define COMPUTE1(b)                                                     \
  {                                                                     \
    short8 af[4], bfr[4];                                               \
    _Pragma("unroll")                                                   \
    for (int i = 0; i < 4; ++i) {                                       \
      af[i]  = *(const short8*)&sA[b][(wr * 64 + i * 16 + frow) * 32 + sl * 8]; \
      bfr[i] = *(const short8*)&sB[b][(wc * 64 + i * 16 + frow) * 32 + sl * 8]; \
    }                                                                   \
    _Pragma("unroll")                                                   \
    for (int i = 0; i < 4; ++i)                                         \
      _Pragma("unroll")                                                 \
      for (int j = 0; j < 4; ++j)                                       \
        acc[i][j] = __builtin_amdgcn_mfma_f32_16x16x32_bf16(af[i], bfr[j], acc[i][j], 0, 0, 0); \
  }

  const int nk = DIM / 32;
  STAGE1(0, 0);
  __syncthreads();
  int cur = 0;
  for (int kt = 0; kt < nk; ++kt) {
    if (kt + 1 < nk) { STAGE1(kt + 1, cur ^ 1); }
    COMPUTE1(cur);
    __syncthreads();
    cur ^= 1;
  }

  float b1v[4];
#pragma unroll
  for (int j = 0; j < 4; ++j)
    b1v[j] = b1g[e * FF + fblk + wc * 64 + j * 16 + frow];

  int rq = lane >> 4;
#pragma unroll
  for (int i = 0; i < 4; ++i) {
#pragma unroll
    for (int r = 0; r < 4; ++r) {
      int m = wr * 64 + i * 16 + rq * 4 + r;
      int row = trow * 128 + m;
      if (row < M) {
        size_t hbase = (size_t)(off + row) * FF;
#pragma unroll
        for (int j = 0; j < 4; ++j) {
          int f = fblk + wc * 64 + j * 16 + frow;
          h[hbase + f] = f2bf(gelu_fast(acc[i][j][r] + b1v[j]));
        }
      }
    }
  }
}

// ---------------- grouped GEMM2: split-K x2 over FF; f32 partials to yp ----------------
// R7 flat mapping (proven 126us). SPLITK=true: blockIdx.y = K-slice, nk=64,
// writes yp[ks][slot][DIM] f32 (combine sums). SPLITK=false: full-K atomic fallback.
template<bool SPLITK>
__global__ __launch_bounds__(512, 4) void gemm2_kernel(const u16* __restrict__ h, const u16* __restrict__ w2b,
                                                       const float* __restrict__ b2g,
                                                       const int* __restrict__ pair_tok, const float* __restrict__ pair_p,
                                                       const int* __restrict__ offsets, const int* __restrict__ counts,
                                                       float* __restrict__ yp, float* __restrict__ out) {
  int lin = blockIdx.x;           // lin = trow*64 + e*8 + dblk_i  (R7 flat)
  int trow = lin >> 6;
  int rem = lin & 63;
  int e = rem >> 3;
  int dblk = (rem & 7) << 7;
  int M = counts[e];
  if (trow * 128 >= M) return;
  int off = offsets[e];
  int ks = SPLITK ? (int)blockIdx.y : 0;
  int kbase = ks * (FF / 2);      // element offset into K

  __shared__ __align__(16) u16 s2A[2][128 * 32];
  __shared__ __align__(16) u16 s2B[2][128 * 32];

  int tid = threadIdx.x, lane = tid & 63, w = tid >> 6;   // w in 0..7
  int wr = w >> 1, wc = w & 1;                            // 4x2 wave grid, wave tile 32x64

  int lr = lane >> 2;
  int cs = (lane & 3) ^ (((lane >> 2) ^ (lane >> 4)) & 3);
  int lrow = w * 16 + lr;                                 // 0..127
  int arow = trow * 128 + lrow;
  int slot_a = off + (arow < M ? arow : M - 1);           // h is SLOT-indexed
  const u16* gA = h + (size_t)slot_a * FF + kbase + cs * 8;
  const u16* gB = w2b + ((size_t)e * DIM + dblk + lrow) * FF + kbase + cs * 8;

  f32x4 acc[2][4];
#pragma unroll
  for (int i = 0; i < 2; ++i)
#pragma unroll
    for (int j = 0; j < 4; ++j)
#pragma unroll
      for (int k = 0; k < 4; ++k) acc[i][j][k] = 0.f;

#define STAGE2(kt, b)                                   \
  {                                                     \
    GLD_LDS(gA + (kt) * 32, &s2A[b][(w * 16) * 32]);    \
    GLD_LDS(gB + (kt) * 32, &s2B[b][(w * 16) * 32]);    \
  }

  int frow = lane & 15, kq = lane >> 4;
  int sl = kq ^ ((frow ^ (frow >> 2)) & 3);

#define COMPUTE2(b)                                                     \
  {                                                                     \
    short8 af[2], bfr[4];                                               \
    _Pragma("unroll")                                                   \
    for (int i = 0; i < 2; ++i)                                         \
      af[i] = *(const short8*)&s2A[b][(wr * 32 + i * 16 + frow) * 32 + sl * 8]; \
    _Pragma("unroll")                                                   \
    for (int j = 0; j < 4; ++j)                                         \
      bfr[j] = *(const short8*)&s2B[b][(wc * 64 + j * 16 + frow) * 32 + sl * 8]; \
    _Pragma("unroll")                                                   \
    for (int i = 0; i < 2; ++i)                                         \
      _Pragma("unroll")                                                 \
      for (int j = 0; j < 4; ++j)                                       \
        acc[i][j] = __builtin_amdgcn_mfma_f32_16x16x32_bf16(af[i], bfr[j], acc[i][j], 0, 0, 0); \
  }

  const int nk = SPLITK ? (FF / 64) : (FF / 32);
  STAGE2(0, 0);
  __syncthreads();
  int cur = 0;
  for (int kt = 0; kt < nk; ++kt) {
    if (kt + 1 < nk) { STAGE2(kt + 1, cur ^ 1); }
    COMPUTE2(cur);
    __syncthreads();
    cur ^= 1;
  }

  int rq = lane >> 4;
#pragma unroll
  for (int i = 0; i < 2; ++i) {
#pragma unroll
    for (int r = 0; r < 4; ++r) {
      int m = wr * 32 + i * 16 + rq * 4 + r;
      int row = trow * 128 + m;
      if (row < M) {
        int slot = off + row;
        if (SPLITK) {
          float* yrow = yp + ((size_t)ks * NPAIR + slot) * DIM;
#pragma unroll
          for (int j = 0; j < 4; ++j) {
            int d = dblk + wc * 64 + j * 16 + frow;
            yrow[d] = acc[i][j][r];
          }
        } else {
          int tk = pair_tok[slot];
          float p = pair_p[slot];
#pragma unroll
          for (int j = 0; j < 4; ++j) {
            int d = dblk + wc * 64 + j * 16 + frow;
            atomicAdd(&out[(size_t)tk * DIM + d], (acc[i][j][r] + b2g[e * DIM + d]) * p);
          }
        }
      }
    }
  }
}

// ---------------- combine: out[tok] = sum_k p_k * (yp0[s_k] + yp1[s_k] + b2[e_k]) ----------------
__global__ __launch_bounds__(256) void combine_kernel(const float* __restrict__ yp, const float* __restrict__ b2,
                                                      const int* __restrict__ inv_slot, const int* __restrict__ tk_e,
                                                      const float* __restrict__ tk_p, float* __restrict__ out) {
  int tok = blockIdx.x;
  int d4 = threadIdx.x;             // 256 threads x 4 floats = 1024 = DIM
  int i0 = tok * 2, i1 = i0 + 1;
  int s0 = inv_slot[i0], s1 = inv_slot[i1];
  int e0 = tk_e[i0],     e1 = tk_e[i1];
  float p0 = tk_p[i0],   p1 = tk_p[i1];
  float4 a0 = *(const float4*)(yp + ((size_t)0 * NPAIR + s0) * DIM + d4 * 4);
  float4 a1 = *(const float4*)(yp + ((size_t)1 * NPAIR + s0) * DIM + d4 * 4);
  float4 c0 = *(const float4*)(yp + ((size_t)0 * NPAIR + s1) * DIM + d4 * 4);
  float4 c1 = *(const float4*)(yp + ((size_t)1 * NPAIR + s1) * DIM + d4 * 4);
  float4 ba = *(const float4*)(b2 + (size_t)e0 * DIM + d4 * 4);
  float4 bb = *(const float4*)(b2 + (size_t)e1 * DIM + d4 * 4);
  float4 r;
  r.x = p0 * (a0.x + a1.x + ba.x) + p1 * (c0.x + c1.x + bb.x);
  r.y = p0 * (a0.y + a1.y + ba.y) + p1 * (c0.y + c1.y + bb.y);
  r.z = p0 * (a0.z + a1.z + ba.z) + p1 * (c0.z + c1.z + bb.z);
  r.w = p0 * (a0.w + a1.w + ba.w) + p1 * (c0.w + c1.w + bb.w);
  *(float4*)(out + (size_t)tok * DIM + d4 * 4) = r;
}

extern "C" void kernel_launch(void* const* d_in, const int* in_sizes, int n_in,
                              void* d_out, int out_size, void* d_ws, size_t ws_size,
                              hipStream_t stream) {
  const float* x  = (const float*)d_in[0];
  const float* gw = (const float*)d_in[1];
  const float* w1 = (const float*)d_in[2];
  const float* b1 = (const float*)d_in[3];
  const float* w2 = (const float*)d_in[4];
  const float* b2 = (const float*)d_in[5];
  float* out = (float*)d_out;

  char* ws = (char*)d_ws;
  size_t o = 0;
  auto alloc = [&](size_t bytes) { void* p = ws + o; o += (bytes + 255) & ~(size_t)255; return p; };
  u16*   xb       = (u16*)alloc((size_t)NTOK * DIM * 2);
  u16*   w1b      = (u16*)alloc((size_t)NE * FF * DIM * 2);
  u16*   w2b      = (u16*)alloc((size_t)NE * DIM * FF * 2);
  u16*   hbuf     = (u16*)alloc((size_t)NPAIR * FF * 2);
  int*   tk_e     = (int*)alloc((size_t)NPAIR * 4);
  float* tk_p     = (float*)alloc((size_t)NPAIR * 4);
  int*   pair_tok = (int*)alloc((size_t)NPAIR * 4);
  float* pair_p   = (float*)alloc((size_t)NPAIR * 4);
  int*   inv_slot = (int*)alloc((size_t)NPAIR * 4);
  int*   pos_buf  = (int*)alloc((size_t)NPAIR * 4);
  int*   bbase    = (int*)alloc((size_t)(NPAIR / 256) * NE * 4);
  int*   counts   = (int*)alloc(NE * 4);
  int*   offsets  = (int*)alloc(NE * 4);
  if (o > ws_size) return;
  float* yp = (float*)(ws + o);
  bool splitk = (o + (size_t)2 * NPAIR * DIM * 4) <= ws_size;   // 64MB f32 partials

  hipMemsetAsync(counts, 0, NE * 4, stream);
  if (!splitk) hipMemsetAsync(out, 0, (size_t)NTOK * DIM * 4, stream);

  gate_kernel  <<<NTOK / 4, 256, 0, stream>>>(x, gw, xb, tk_e, tk_p);
  route_count_kernel<<<NPAIR / 256, 256, 0, stream>>>(tk_e, counts, bbase, pos_buf);
  route_offsets_kernel<<<1, 64, 0, stream>>>(counts, offsets);
  scatter_kernel<<<NPAIR / 256, 256, 0, stream>>>(tk_e, tk_p, offsets, bbase, pos_buf,
                                                  pair_tok, pair_p, inv_slot);
  cvt_w1_kernel<<<NE * FF * DIM / 4 / 256, 256, 0, stream>>>(w1, w1b);
  cvt_w2_kernel<<<NE * DIM * FF / 4 / 256, 256, 0, stream>>>(w2, w2b);
  gemm1_kernel<<<NE * 32 * 32, 256, 0, stream>>>(xb, w1b, b1, pair_tok, offsets, counts, hbuf);
  if (splitk) {
    gemm2_kernel<true><<<dim3(NE * 32 * 8, 2), 512, 0, stream>>>(hbuf, w2b, b2, pair_tok, pair_p,
                                                                 offsets, counts, yp, out);
    combine_kernel<<<NTOK, 256, 0, stream>>>(yp, b2, inv_slot, tk_e, tk_p, out);
  } else {
    gemm2_kernel<false><<<NE * 32 * 8, 512, 0, stream>>>(hbuf, w2b, b2, pair_tok, pair_p,
                                                         offsets, counts, yp, out);
  }
}

// Round 15
// 348.872 us; speedup vs baseline: 1.0371x; 1.0371x over previous
//
#include <hip/hip_runtime.h>
#include <hip/hip_bf16.h>
#include <stdint.h>

#define NTOK 4096      // B*S
#define DIM  1024      // D
#define FF   4096      // F
#define NE   8         // experts
#define NPAIR (NTOK*2) // top-2

using short8 = __attribute__((ext_vector_type(8))) short;
using f32x4  = __attribute__((ext_vector_type(4))) float;
typedef unsigned short u16;
typedef unsigned int   u32;

#define GLD_LDS(gp, lp) \
  __builtin_amdgcn_global_load_lds((const __attribute__((address_space(1))) void*)(gp), \
                                   (__attribute__((address_space(3))) void*)(lp), 16, 0, 0)

__device__ __forceinline__ u16 f2bf(float f) {
  union { float f; u32 u; } v; v.f = f;
  u32 r = (v.u + 0x7fffu + ((v.u >> 16) & 1u)) >> 16;
  return (u16)r;
}
__device__ __forceinline__ float bf2f(u16 u) {
  union { u32 u; float f; } v; v.u = (u32)u << 16; return v.f;
}
__device__ __forceinline__ u32 pack2(float lo, float hi) {
  return (u32)f2bf(lo) | ((u32)f2bf(hi) << 16);
}
// exact rewrite of tanh-gelu: 0.5x(1+tanh(z)) == x * sigmoid(2z)
__device__ __forceinline__ float gelu_fast(float x) {
  float t = x * (-1.5957691216057308f - 0.07135481627822202f * x * x); // -2z
  return x / (1.0f + __expf(t));
}

// ---------------- weight conversions f32 -> bf16 (relayout per-expert) ----------------
__global__ __launch_bounds__(256) void cvt_w1_kernel(const float* __restrict__ w1, u16* __restrict__ w1b) {
  // in: [F][E][D]  ->  out: [E][F][D]
  size_t i4 = (size_t)blockIdx.x * 256 + threadIdx.x;
  int d4 = (int)(i4 & (DIM/4 - 1));
  size_t t = i4 >> 8;
  int f = (int)(t & (FF - 1));
  int e = (int)(t >> 12);
  float4 v = *(const float4*)(w1 + ((size_t)f * NE + e) * DIM + (size_t)d4 * 4);
  *(uint2*)(w1b + ((size_t)e * FF + f) * DIM + (size_t)d4 * 4) =
      make_uint2(pack2(v.x, v.y), pack2(v.z, v.w));
}

__global__ __launch_bounds__(256) void cvt_w2_kernel(const float* __restrict__ w2, u16* __restrict__ w2b) {
  // in: [D][E][F]  ->  out: [E][D][F]
  size_t i4 = (size_t)blockIdx.x * 256 + threadIdx.x;
  int f4 = (int)(i4 & (FF/4 - 1));
  size_t t = i4 >> 10;
  int d = (int)(t & (DIM - 1));
  int e = (int)(t >> 10);
  float4 v = *(const float4*)(w2 + ((size_t)d * NE + e) * FF + (size_t)f4 * 4);
  *(uint2*)(w2b + ((size_t)e * DIM + d) * FF + (size_t)f4 * 4) =
      make_uint2(pack2(v.x, v.y), pack2(v.z, v.w));
}

// ---------------- gating (fused with x -> bf16 cast); NO global atomics ----------------
__global__ __launch_bounds__(256) void gate_kernel(const float* __restrict__ x, const float* __restrict__ gw,
                                                   u16* __restrict__ xb,
                                                   int* __restrict__ tk_e, float* __restrict__ tk_p) {
  int tok  = blockIdx.x * 4 + (threadIdx.x >> 6);
  int lane = threadIdx.x & 63;
  const float* xr = x + (size_t)tok * DIM;
  u16* xw = xb + (size_t)tok * DIM;
  float acc[NE];
#pragma unroll
  for (int e = 0; e < NE; ++e) acc[e] = 0.f;
#pragma unroll
  for (int it = 0; it < 4; ++it) {
    int d = it * 256 + lane * 4;
    float4 xv = *(const float4*)(xr + d);
    *(uint2*)(xw + d) = make_uint2(pack2(xv.x, xv.y), pack2(xv.z, xv.w));
#pragma unroll
    for (int e = 0; e < NE; ++e) {
      float4 gv = *(const float4*)(gw + (size_t)e * DIM + d);
      acc[e] += xv.x * gv.x + xv.y * gv.y + xv.z * gv.z + xv.w * gv.w;
    }
  }
#pragma unroll
  for (int e = 0; e < NE; ++e)
#pragma unroll
    for (int off = 32; off; off >>= 1) acc[e] += __shfl_xor(acc[e], off);

  if (lane == 0) {
    float mx = acc[0];
#pragma unroll
    for (int e = 1; e < NE; ++e) mx = fmaxf(mx, acc[e]);
    float pr[NE]; float s = 0.f;
#pragma unroll
    for (int e = 0; e < NE; ++e) { pr[e] = __expf(acc[e] - mx); s += pr[e]; }
    float inv = 1.f / s;
    int e0 = 0; float p0 = pr[0];
#pragma unroll
    for (int e = 1; e < NE; ++e) if (pr[e] > p0) { p0 = pr[e]; e0 = e; }
    int e1 = (e0 == 0) ? 1 : 0; float p1 = pr[e1];
#pragma unroll
    for (int e = 0; e < NE; ++e) if (e != e0 && pr[e] > p1) { p1 = pr[e]; e1 = e; }
    tk_e[tok * 2]     = e0; tk_p[tok * 2]     = p0 * inv;
    tk_e[tok * 2 + 1] = e1; tk_p[tok * 2 + 1] = p1 * inv;
  }
}

// ---------------- routing: LDS histogram, 8 global atomics per block (G12) ----------------
__global__ __launch_bounds__(256) void route_count_kernel(const int* __restrict__ tk_e,
                                                          int* __restrict__ counts,
                                                          int* __restrict__ bbase,
                                                          int* __restrict__ pos_buf) {
  __shared__ int hist[NE];
  if (threadIdx.x < NE) hist[threadIdx.x] = 0;
  __syncthreads();
  int i = blockIdx.x * 256 + threadIdx.x;
  int e = tk_e[i];
  pos_buf[i] = atomicAdd(&hist[e], 1);
  __syncthreads();
  if (threadIdx.x < NE) {
    int c = hist[threadIdx.x];
    bbase[blockIdx.x * NE + threadIdx.x] = atomicAdd(&counts[threadIdx.x], c);
  }
}

__global__ void route_offsets_kernel(const int* __restrict__ counts, int* __restrict__ offsets) {
  if (threadIdx.x == 0) { int s = 0; for (int e = 0; e < NE; ++e) { offsets[e] = s; s += counts[e]; } }
}

__global__ __launch_bounds__(256) void scatter_kernel(const int* __restrict__ tk_e, const float* __restrict__ tk_p,
                                                      const int* __restrict__ offsets,
                                                      const int* __restrict__ bbase, const int* __restrict__ pos_buf,
                                                      int* __restrict__ pair_tok, float* __restrict__ pair_p,
                                                      int* __restrict__ inv_slot) {
  int i = blockIdx.x * 256 + threadIdx.x;
  int e = tk_e[i];
  int slot = offsets[e] + bbase[blockIdx.x * NE + e] + pos_buf[i];
  pair_tok[slot] = i >> 1;
  pair_p[slot]   = tk_p[i];
  inv_slot[i]    = slot;
}

// ---------------- grouped GEMM1: h[slot] = gelu(x[tok(slot)] @ w1_e^T + b1_e) ----------------
// R7-proven body (128x128, BK=32, gld_lds, dbuf 32KB, 2-phase).
// R12-proven mapping: XCD-chunked, trow-inner (32 panel-sharing blocks contiguous per XCD).
__global__ __launch_bounds__(256, 4) void gemm1_kernel(const u16* __restrict__ xb, const u16* __restrict__ w1b,
                                                       const float* __restrict__ b1g,
                                                       const int* __restrict__ pair_tok,
                                                       const int* __restrict__ offsets, const int* __restrict__ counts,
                                                       u16* __restrict__ h) {
  // nwg = 8192; chunk = 1024 per XCD. logical = (e*32+fb)*32 + trow (trow inner).
  int logical = (blockIdx.x & 7) * 1024 + (blockIdx.x >> 3);
  int trow = logical & 31;
  int rem = logical >> 5;          // e*32 + fb
  int e = rem >> 5;
  int fblk = (rem & 31) << 7;
  int M = counts[e];
  if (trow * 128 >= M) return;
  int off = offsets[e];

  __shared__ __align__(16) u16 sA[2][128 * 32];
  __shared__ __align__(16) u16 sB[2][128 * 32];

  int tid = threadIdx.x, lane = tid & 63, w = tid >> 6;
  int wr = w >> 1, wc = w & 1;

  // staging: instr c covers rows c*64 + w*16 + (lane>>2); 16B slot cs swizzled
  int lr = lane >> 2;
  int cs = (lane & 3) ^ (((lane >> 2) ^ (lane >> 4)) & 3);
  const u16* gA[2]; const u16* gB[2];
#pragma unroll
  for (int cc = 0; cc < 2; ++cc) {
    int lrow = cc * 64 + w * 16 + lr;
    int arow = trow * 128 + lrow;
    int tok = pair_tok[off + (arow < M ? arow : M - 1)];
    gA[cc] = xb + (size_t)tok * DIM + cs * 8;
    gB[cc] = w1b + ((size_t)e * FF + fblk + lrow) * DIM + cs * 8;
  }

  f32x4 acc[4][4];
#pragma unroll
  for (int i = 0; i < 4; ++i)
#pragma unroll
    for (int j = 0; j < 4; ++j)
#pragma unroll
      for (int k = 0; k < 4; ++k) acc[i][j][k] = 0.f;

#define STAGE1(kt, b)                                                   \
  _Pragma("unroll")                                                     \
  for (int cc = 0; cc < 2; ++cc) {                                      \
    GLD_LDS(gA[cc] + (kt) * 32, &sA[b][(cc * 64 + w * 16) * 32]);       \
    GLD_LDS(gB[cc] + (kt) * 32, &sB[b][(cc * 64 + w * 16) * 32]);       \
  }

  int frow = lane & 15, kq = lane >> 4;
  int sl = kq ^ ((frow ^ (frow >> 2)) & 3);

#define COMPUTE1(b)                                                     \
  {                                                                     \
    short8 af[4], bfr[4];                                               \
    _Pragma("unroll")                                                   \
    for (int i = 0; i < 4; ++i) {                                       \
      af[i]  = *(const short8*)&sA[b][(wr * 64 + i * 16 + frow) * 32 + sl * 8]; \
      bfr[i] = *(const short8*)&sB[b][(wc * 64 + i * 16 + frow) * 32 + sl * 8]; \
    }                                                                   \
    _Pragma("unroll")                                                   \
    for (int i = 0; i < 4; ++i)                                         \
      _Pragma("unroll")                                                 \
      for (int j = 0; j < 4; ++j)                                       \
        acc[i][j] = __builtin_amdgcn_mfma_f32_16x16x32_bf16(af[i], bfr[j], acc[i][j], 0, 0, 0); \
  }

  const int nk = DIM / 32;
  STAGE1(0, 0);
  __syncthreads();
  int cur = 0;
  for (int kt = 0; kt < nk; ++kt) {
    if (kt + 1 < nk) { STAGE1(kt + 1, cur ^ 1); }
    COMPUTE1(cur);
    __syncthreads();
    cur ^= 1;
  }

  // epilogue: bias + fast gelu + bf16 store
  float b1v[4];
#pragma unroll
  for (int j = 0; j < 4; ++j)
    b1v[j] = b1g[e * FF + fblk + wc * 64 + j * 16 + frow];

  int rq = lane >> 4;
#pragma unroll
  for (int i = 0; i < 4; ++i) {
#pragma unroll
    for (int r = 0; r < 4; ++r) {
      int m = wr * 64 + i * 16 + rq * 4 + r;
      int row = trow * 128 + m;
      if (row < M) {
        size_t hbase = (size_t)(off + row) * FF;
#pragma unroll
        for (int j = 0; j < 4; ++j) {
          int f = fblk + wc * 64 + j * 16 + frow;
          h[hbase + f] = f2bf(gelu_fast(acc[i][j][r] + b1v[j]));
        }
      }
    }
  }
}

// ---------------- grouped GEMM2 (R7-proven, 512 thr, 8 waves, flat mapping) ----------------
template<bool SPLIT>
__global__ __launch_bounds__(512, 4) void gemm2_kernel(const u16* __restrict__ h, const u16* __restrict__ w2b,
                                                       const float* __restrict__ b2g,
                                                       const int* __restrict__ pair_tok, const float* __restrict__ pair_p,
                                                       const int* __restrict__ offsets, const int* __restrict__ counts,
                                                       u16* __restrict__ yb, float* __restrict__ out) {
  int lin = blockIdx.x;           // lin = trow*64 + e*8 + dblk_i  (R7 flat)
  int trow = lin >> 6;
  int rem = lin & 63;
  int e = rem >> 3;
  int dblk = (rem & 7) << 7;
  int M = counts[e];
  if (trow * 128 >= M) return;
  int off = offsets[e];

  __shared__ __align__(16) u16 s2A[2][128 * 32];
  __shared__ __align__(16) u16 s2B[2][128 * 32];

  int tid = threadIdx.x, lane = tid & 63, w = tid >> 6;   // w in 0..7
  int wr = w >> 1, wc = w & 1;                            // 4x2 wave grid, wave tile 32x64

  int lr = lane >> 2;
  int cs = (lane & 3) ^ (((lane >> 2) ^ (lane >> 4)) & 3);
  int lrow = w * 16 + lr;                                 // 0..127
  int arow = trow * 128 + lrow;
  int slot_a = off + (arow < M ? arow : M - 1);           // h is SLOT-indexed
  const u16* gA = h + (size_t)slot_a * FF + cs * 8;
  const u16* gB = w2b + ((size_t)e * DIM + dblk + lrow) * FF + cs * 8;

  f32x4 acc[2][4];
#pragma unroll
  for (int i = 0; i < 2; ++i)
#pragma unroll
    for (int j = 0; j < 4; ++j)
#pragma unroll
      for (int k = 0; k < 4; ++k) acc[i][j][k] = 0.f;

#define STAGE2(kt, b)                                   \
  {                                                     \
    GLD_LDS(gA + (kt) * 32, &s2A[b][(w * 16) * 32]);    \
    GLD_LDS(gB + (kt) * 32, &s2B[b][(w * 16) * 32]);    \
  }

  int frow = lane & 15, kq = lane >> 4;
  int sl = kq ^ ((frow ^ (frow >> 2)) & 3);

#define COMPUTE2(b)                                                     \
  {                                                                     \
    short8 af[2], bfr[4];                                               \
    _Pragma("unroll")                                                   \
    for (int i = 0; i < 2; ++i)                                         \
      af[i] = *(const short8*)&s2A[b][(wr * 32 + i * 16 + frow) * 32 + sl * 8]; \
    _Pragma("unroll")                                                   \
    for (int j = 0; j < 4; ++j)                                         \
      bfr[j] = *(const short8*)&s2B[b][(wc * 64 + j * 16 + frow) * 32 + sl * 8]; \
    _Pragma("unroll")                                                   \
    for (int i = 0; i < 2; ++i)                                         \
      _Pragma("unroll")                                                 \
      for (int j = 0; j < 4; ++j)                                       \
        acc[i][j] = __builtin_amdgcn_mfma_f32_16x16x32_bf16(af[i], bfr[j], acc[i][j], 0, 0, 0); \
  }

  const int nk = FF / 32;
  STAGE2(0, 0);
  __syncthreads();
  int cur = 0;
  for (int kt = 0; kt < nk; ++kt) {
    if (kt + 1 < nk) { STAGE2(kt + 1, cur ^ 1); }
    COMPUTE2(cur);
    __syncthreads();
    cur ^= 1;
  }

  int rq = lane >> 4;
#pragma unroll
  for (int i = 0; i < 2; ++i) {
#pragma unroll
    for (int r = 0; r < 4; ++r) {
      int m = wr * 32 + i * 16 + rq * 4 + r;
      int row = trow * 128 + m;
      if (row < M) {
        int slot = off + row;
        if (SPLIT) {
#pragma unroll
          for (int j = 0; j < 4; ++j) {
            int d = dblk + wc * 64 + j * 16 + frow;
            yb[(size_t)slot * DIM + d] = f2bf(acc[i][j][r]);
          }
        } else {
          int tk = pair_tok[slot];
          float p = pair_p[slot];
#pragma unroll
          for (int j = 0; j < 4; ++j) {
            int d = dblk + wc * 64 + j * 16 + frow;
            atomicAdd(&out[(size_t)tk * DIM + d], (acc[i][j][r] + b2g[e * DIM + d]) * p);
          }
        }
      }
    }
  }
}

// ---------------- combine: out[tok] = sum_k p_k * (y_k + b2[e_k]) ----------------
__global__ __launch_bounds__(256) void combine_kernel(const u16* __restrict__ yb, const float* __restrict__ b2,
                                                      const int* __restrict__ inv_slot, const int* __restrict__ tk_e,
                                                      const float* __restrict__ tk_p, float* __restrict__ out) {
  int tok = blockIdx.x;
  int d4 = threadIdx.x;             // 256 threads x 4 floats = 1024 = DIM
  int i0 = tok * 2, i1 = i0 + 1;
  int s0 = inv_slot[i0], s1 = inv_slot[i1];
  int e0 = tk_e[i0],     e1 = tk_e[i1];
  float p0 = tk_p[i0],   p1 = tk_p[i1];
  uint2 ya = *(const uint2*)(yb + (size_t)s0 * DIM + d4 * 4);
  uint2 yc = *(const uint2*)(yb + (size_t)s1 * DIM + d4 * 4);
  float4 ba = *(const float4*)(b2 + (size_t)e0 * DIM + d4 * 4);
  float4 bb = *(const float4*)(b2 + (size_t)e1 * DIM + d4 * 4);
  float4 r;
  r.x = p0 * (bf2f((u16)(ya.x & 0xffff)) + ba.x) + p1 * (bf2f((u16)(yc.x & 0xffff)) + bb.x);
  r.y = p0 * (bf2f((u16)(ya.x >> 16))   + ba.y) + p1 * (bf2f((u16)(yc.x >> 16))   + bb.y);
  r.z = p0 * (bf2f((u16)(ya.y & 0xffff)) + ba.z) + p1 * (bf2f((u16)(yc.y & 0xffff)) + bb.z);
  r.w = p0 * (bf2f((u16)(ya.y >> 16))   + ba.w) + p1 * (bf2f((u16)(yc.y >> 16))   + bb.w);
  *(float4*)(out + (size_t)tok * DIM + d4 * 4) = r;
}

extern "C" void kernel_launch(void* const* d_in, const int* in_sizes, int n_in,
                              void* d_out, int out_size, void* d_ws, size_t ws_size,
                              hipStream_t stream) {
  const float* x  = (const float*)d_in[0];
  const float* gw = (const float*)d_in[1];
  const float* w1 = (const float*)d_in[2];
  const float* b1 = (const float*)d_in[3];
  const float* w2 = (const float*)d_in[4];
  const float* b2 = (const float*)d_in[5];
  float* out = (float*)d_out;

  char* ws = (char*)d_ws;
  size_t o = 0;
  auto alloc = [&](size_t bytes) { void* p = ws + o; o += (bytes + 255) & ~(size_t)255; return p; };
  u16*   xb       = (u16*)alloc((size_t)NTOK * DIM * 2);
  u16*   w1b      = (u16*)alloc((size_t)NE * FF * DIM * 2);
  u16*   w2b      = (u16*)alloc((size_t)NE * DIM * FF * 2);
  u16*   hbuf     = (u16*)alloc((size_t)NPAIR * FF * 2);
  int*   tk_e     = (int*)alloc((size_t)NPAIR * 4);
  float* tk_p     = (float*)alloc((size_t)NPAIR * 4);
  int*   pair_tok = (int*)alloc((size_t)NPAIR * 4);
  float* pair_p   = (float*)alloc((size_t)NPAIR * 4);
  int*   inv_slot = (int*)alloc((size_t)NPAIR * 4);
  int*   pos_buf  = (int*)alloc((size_t)NPAIR * 4);
  int*   bbase    = (int*)alloc((size_t)(NPAIR / 256) * NE * 4);
  int*   counts   = (int*)alloc(NE * 4);
  int*   offsets  = (int*)alloc(NE * 4);
  if (o > ws_size) return;
  u16* yb = (u16*)(ws + o);
  bool split = (o + (size_t)NPAIR * DIM * 2) <= ws_size;   // 16MB extra for y buffer

  hipMemsetAsync(counts, 0, NE * 4, stream);
  if (!split) hipMemsetAsync(out, 0, (size_t)NTOK * DIM * 4, stream);

  gate_kernel  <<<NTOK / 4, 256, 0, stream>>>(x, gw, xb, tk_e, tk_p);
  route_count_kernel<<<NPAIR / 256, 256, 0, stream>>>(tk_e, counts, bbase, pos_buf);
  route_offsets_kernel<<<1, 64, 0, stream>>>(counts, offsets);
  scatter_kernel<<<NPAIR / 256, 256, 0, stream>>>(tk_e, tk_p, offsets, bbase, pos_buf,
                                                  pair_tok, pair_p, inv_slot);
  cvt_w1_kernel<<<NE * FF * DIM / 4 / 256, 256, 0, stream>>>(w1, w1b);
  cvt_w2_kernel<<<NE * DIM * FF / 4 / 256, 256, 0, stream>>>(w2, w2b);
  gemm1_kernel<<<NE * 32 * 32, 256, 0, stream>>>(xb, w1b, b1, pair_tok, offsets, counts, hbuf);
  if (split) {
    gemm2_kernel<true><<<NE * 32 * 8, 512, 0, stream>>>(hbuf, w2b, b2, pair_tok, pair_p, offsets, counts, yb, out);
    combine_kernel<<<NTOK, 256, 0, stream>>>(yb, b2, inv_slot, tk_e, tk_p, out);
  } else {
    gemm2_kernel<false><<<NE * 32 * 8, 512, 0, stream>>>(hbuf, w2b, b2, pair_tok, pair_p, offsets, counts, yb, out);
  }
}

// Round 16
// 341.911 us; speedup vs baseline: 1.0582x; 1.0204x over previous
//
#include <hip/hip_runtime.h>
#include <hip/hip_bf16.h>
#include <stdint.h>

#define NTOK 4096      // B*S
#define DIM  1024      // D
#define FF   4096      // F
#define NE   8         // experts
#define NPAIR (NTOK*2) // top-2

using short8 = __attribute__((ext_vector_type(8))) short;
using f32x4  = __attribute__((ext_vector_type(4))) float;
typedef unsigned short u16;
typedef unsigned int   u32;

#define GLD_LDS(gp, lp) \
  __builtin_amdgcn_global_load_lds((const __attribute__((address_space(1))) void*)(gp), \
                                   (__attribute__((address_space(3))) void*)(lp), 16, 0, 0)

__device__ __forceinline__ u16 f2bf(float f) {
  union { float f; u32 u; } v; v.f = f;
  u32 r = (v.u + 0x7fffu + ((v.u >> 16) & 1u)) >> 16;
  return (u16)r;
}
__device__ __forceinline__ float bf2f(u16 u) {
  union { u32 u; float f; } v; v.u = (u32)u << 16; return v.f;
}
__device__ __forceinline__ u32 pack2(float lo, float hi) {
  return (u32)f2bf(lo) | ((u32)f2bf(hi) << 16);
}
// exact rewrite of tanh-gelu: 0.5x(1+tanh(z)) == x * sigmoid(2z)
__device__ __forceinline__ float gelu_fast(float x) {
  float t = x * (-1.5957691216057308f - 0.07135481627822202f * x * x); // -2z
  return x / (1.0f + __expf(t));
}

// ---------------- weight conversion f32 -> bf16 (w1: [F][E][D] -> [E][F][D]) ----------------
__global__ __launch_bounds__(256) void cvt_w1_kernel(const float* __restrict__ w1, u16* __restrict__ w1b) {
  size_t i4 = (size_t)blockIdx.x * 256 + threadIdx.x;
  int d4 = (int)(i4 & (DIM/4 - 1));
  size_t t = i4 >> 8;
  int f = (int)(t & (FF - 1));
  int e = (int)(t >> 12);
  float4 v = *(const float4*)(w1 + ((size_t)f * NE + e) * DIM + (size_t)d4 * 4);
  *(uint2*)(w1b + ((size_t)e * FF + f) * DIM + (size_t)d4 * 4) =
      make_uint2(pack2(v.x, v.y), pack2(v.z, v.w));
}

// ---------------- gating (fused with x -> bf16 cast); NO global atomics ----------------
__global__ __launch_bounds__(256) void gate_kernel(const float* __restrict__ x, const float* __restrict__ gw,
                                                   u16* __restrict__ xb,
                                                   int* __restrict__ tk_e, float* __restrict__ tk_p) {
  int tok  = blockIdx.x * 4 + (threadIdx.x >> 6);
  int lane = threadIdx.x & 63;
  const float* xr = x + (size_t)tok * DIM;
  u16* xw = xb + (size_t)tok * DIM;
  float acc[NE];
#pragma unroll
  for (int e = 0; e < NE; ++e) acc[e] = 0.f;
#pragma unroll
  for (int it = 0; it < 4; ++it) {
    int d = it * 256 + lane * 4;
    float4 xv = *(const float4*)(xr + d);
    *(uint2*)(xw + d) = make_uint2(pack2(xv.x, xv.y), pack2(xv.z, xv.w));
#pragma unroll
    for (int e = 0; e < NE; ++e) {
      float4 gv = *(const float4*)(gw + (size_t)e * DIM + d);
      acc[e] += xv.x * gv.x + xv.y * gv.y + xv.z * gv.z + xv.w * gv.w;
    }
  }
#pragma unroll
  for (int e = 0; e < NE; ++e)
#pragma unroll
    for (int off = 32; off; off >>= 1) acc[e] += __shfl_xor(acc[e], off);

  if (lane == 0) {
    float mx = acc[0];
#pragma unroll
    for (int e = 1; e < NE; ++e) mx = fmaxf(mx, acc[e]);
    float pr[NE]; float s = 0.f;
#pragma unroll
    for (int e = 0; e < NE; ++e) { pr[e] = __expf(acc[e] - mx); s += pr[e]; }
    float inv = 1.f / s;
    int e0 = 0; float p0 = pr[0];
#pragma unroll
    for (int e = 1; e < NE; ++e) if (pr[e] > p0) { p0 = pr[e]; e0 = e; }
    int e1 = (e0 == 0) ? 1 : 0; float p1 = pr[e1];
#pragma unroll
    for (int e = 0; e < NE; ++e) if (e != e0 && pr[e] > p1) { p1 = pr[e]; e1 = e; }
    tk_e[tok * 2]     = e0; tk_p[tok * 2]     = p0 * inv;
    tk_e[tok * 2 + 1] = e1; tk_p[tok * 2 + 1] = p1 * inv;
  }
}

// ---------------- routing: LDS histogram, 8 global atomics per block (G12) ----------------
__global__ __launch_bounds__(256) void route_count_kernel(const int* __restrict__ tk_e,
                                                          int* __restrict__ counts,
                                                          int* __restrict__ bbase,
                                                          int* __restrict__ pos_buf) {
  __shared__ int hist[NE];
  if (threadIdx.x < NE) hist[threadIdx.x] = 0;
  __syncthreads();
  int i = blockIdx.x * 256 + threadIdx.x;
  int e = tk_e[i];
  pos_buf[i] = atomicAdd(&hist[e], 1);
  __syncthreads();
  if (threadIdx.x < NE) {
    int c = hist[threadIdx.x];
    bbase[blockIdx.x * NE + threadIdx.x] = atomicAdd(&counts[threadIdx.x], c);
  }
}

__global__ void route_offsets_kernel(const int* __restrict__ counts, int* __restrict__ offsets) {
  if (threadIdx.x == 0) { int s = 0; for (int e = 0; e < NE; ++e) { offsets[e] = s; s += counts[e]; } }
}

__global__ __launch_bounds__(256) void scatter_kernel(const int* __restrict__ tk_e, const float* __restrict__ tk_p,
                                                      const int* __restrict__ offsets,
                                                      const int* __restrict__ bbase, const int* __restrict__ pos_buf,
                                                      int* __restrict__ pair_tok, float* __restrict__ pair_p,
                                                      int* __restrict__ inv_slot) {
  int i = blockIdx.x * 256 + threadIdx.x;
  int e = tk_e[i];
  int slot = offsets[e] + bbase[blockIdx.x * NE + e] + pos_buf[i];
  pair_tok[slot] = i >> 1;
  pair_p[slot]   = tk_p[i];
  inv_slot[i]    = slot;
}

// ---------------- grouped GEMM1 + fused cvt_w2 backfill ----------------
// Blocks [0, 8192): R7-proven GEMM1 (128x128, BK=32, gld_lds, dbuf 32KB, 2-phase, flat map).
// Blocks [8192, 40960): cvt_w2 f32->bf16 relayout ([D][E][F] -> [E][D][F]) — pure-BW work
// backfilled into gemm1's stall bubbles / early-exit slots (gemm1 uses only ~35% of HBM BW).
// Kernel boundary syncs w2b before gemm2 reads it.
__global__ __launch_bounds__(256, 4) void gemm1_kernel(const u16* __restrict__ xb, const u16* __restrict__ w1b,
                                                       const float* __restrict__ b1g,
                                                       const int* __restrict__ pair_tok,
                                                       const int* __restrict__ offsets, const int* __restrict__ counts,
                                                       u16* __restrict__ h,
                                                       const float* __restrict__ w2, u16* __restrict__ w2b) {
  if (blockIdx.x >= NE * 32 * 32) {
    // ---- cvt_w2 body: [D][E][F] -> [E][D][F] ----
    size_t i4 = (size_t)(blockIdx.x - NE * 32 * 32) * 256 + threadIdx.x;
    int f4 = (int)(i4 & (FF/4 - 1));
    size_t t = i4 >> 10;
    int d = (int)(t & (DIM - 1));
    int e = (int)(t >> 10);
    float4 v = *(const float4*)(w2 + ((size_t)d * NE + e) * FF + (size_t)f4 * 4);
    *(uint2*)(w2b + ((size_t)e * DIM + d) * FF + (size_t)f4 * 4) =
        make_uint2(pack2(v.x, v.y), pack2(v.z, v.w));
    return;
  }

  int lin = blockIdx.x;           // lin = trow*256 + e*32 + fblk_i  (R7 flat)
  int trow = lin >> 8;
  int rem = lin & 255;
  int e = rem >> 5;
  int fblk = (rem & 31) << 7;
  int M = counts[e];
  if (trow * 128 >= M) return;
  int off = offsets[e];

  __shared__ __align__(16) u16 sA[2][128 * 32];
  __shared__ __align__(16) u16 sB[2][128 * 32];

  int tid = threadIdx.x, lane = tid & 63, w = tid >> 6;
  int wr = w >> 1, wc = w & 1;

  // staging: instr c covers rows c*64 + w*16 + (lane>>2); 16B slot cs swizzled
  int lr = lane >> 2;
  int cs = (lane & 3) ^ (((lane >> 2) ^ (lane >> 4)) & 3);
  const u16* gA[2]; const u16* gB[2];
#pragma unroll
  for (int cc = 0; cc < 2; ++cc) {
    int lrow = cc * 64 + w * 16 + lr;
    int arow = trow * 128 + lrow;
    int tok = pair_tok[off + (arow < M ? arow : M - 1)];
    gA[cc] = xb + (size_t)tok * DIM + cs * 8;
    gB[cc] = w1b + ((size_t)e * FF + fblk + lrow) * DIM + cs * 8;
  }

  f32x4 acc[4][4];
#pragma unroll
  for (int i = 0; i < 4; ++i)
#pragma unroll
    for (int j = 0; j < 4; ++j)
#pragma unroll
      for (int k = 0; k < 4; ++k) acc[i][j][k] = 0.f;

#define STAGE1(kt, b)                                                   \
  _Pragma("unroll")                                                     \
  for (int cc = 0; cc < 2; ++cc) {                                      \
    GLD_LDS(gA[cc] + (kt) * 32, &sA[b][(cc * 64 + w * 16) * 32]);       \
    GLD_LDS(gB[cc] + (kt) * 32, &sB[b][(cc * 64 + w * 16) * 32]);       \
  }

  int frow = lane & 15, kq = lane >> 4;
  int sl = kq ^ ((frow ^ (frow >> 2)) & 3);

#define COMPUTE1(b)                                                     \
  {                                                                     \
    short8 af[4], bfr[4];                                               \
    _Pragma("unroll")                                                   \
    for (int i = 0; i < 4; ++i) {                                       \
      af[i]  = *(const short8*)&sA[b][(wr * 64 + i * 16 + frow) * 32 + sl * 8]; \
      bfr[i] = *(const short8*)&sB[b][(wc * 64 + i * 16 + frow) * 32 + sl * 8]; \
    }                                                                   \
    _Pragma("unroll")                                                   \
    for (int i = 0; i < 4; ++i)                                         \
      _Pragma("unroll")                                                 \
      for (int j = 0; j < 4; ++j)                                       \
        acc[i][j] = __builtin_amdgcn_mfma_f32_16x16x32_bf16(af[i], bfr[j], acc[i][j], 0, 0, 0); \
  }

  const int nk = DIM / 32;
  STAGE1(0, 0);
  __syncthreads();
  int cur = 0;
  for (int kt = 0; kt < nk; ++kt) {
    if (kt + 1 < nk) { STAGE1(kt + 1, cur ^ 1); }
    COMPUTE1(cur);
    __syncthreads();
    cur ^= 1;
  }

  // epilogue: bias + fast gelu + bf16 store
  float b1v[4];
#pragma unroll
  for (int j = 0; j < 4; ++j)
    b1v[j] = b1g[e * FF + fblk + wc * 64 + j * 16 + frow];

  int rq = lane >> 4;
#pragma unroll
  for (int i = 0; i < 4; ++i) {
#pragma unroll
    for (int r = 0; r < 4; ++r) {
      int m = wr * 64 + i * 16 + rq * 4 + r;
      int row = trow * 128 + m;
      if (row < M) {
        size_t hbase = (size_t)(off + row) * FF;
#pragma unroll
        for (int j = 0; j < 4; ++j) {
          int f = fblk + wc * 64 + j * 16 + frow;
          h[hbase + f] = f2bf(gelu_fast(acc[i][j][r] + b1v[j]));
        }
      }
    }
  }
}

// ---------------- grouped GEMM2 (R7-proven, 512 thr, 8 waves, flat mapping) ----------------
template<bool SPLIT>
__global__ __launch_bounds__(512, 4) void gemm2_kernel(const u16* __restrict__ h, const u16* __restrict__ w2b,
                                                       const float* __restrict__ b2g,
                                                       const int* __restrict__ pair_tok, const float* __restrict__ pair_p,
                                                       const int* __restrict__ offsets, const int* __restrict__ counts,
                                                       u16* __restrict__ yb, float* __restrict__ out) {
  int lin = blockIdx.x;           // lin = trow*64 + e*8 + dblk_i  (R7 flat)
  int trow = lin >> 6;
  int rem = lin & 63;
  int e = rem >> 3;
  int dblk = (rem & 7) << 7;
  int M = counts[e];
  if (trow * 128 >= M) return;
  int off = offsets[e];

  __shared__ __align__(16) u16 s2A[2][128 * 32];
  __shared__ __align__(16) u16 s2B[2][128 * 32];

  int tid = threadIdx.x, lane = tid & 63, w = tid >> 6;   // w in 0..7
  int wr = w >> 1, wc = w & 1;                            // 4x2 wave grid, wave tile 32x64

  int lr = lane >> 2;
  int cs = (lane & 3) ^ (((lane >> 2) ^ (lane >> 4)) & 3);
  int lrow = w * 16 + lr;                                 // 0..127
  int arow = trow * 128 + lrow;
  int slot_a = off + (arow < M ? arow : M - 1);           // h is SLOT-indexed
  const u16* gA = h + (size_t)slot_a * FF + cs * 8;
  const u16* gB = w2b + ((size_t)e * DIM + dblk + lrow) * FF + cs * 8;

  f32x4 acc[2][4];
#pragma unroll
  for (int i = 0; i < 2; ++i)
#pragma unroll
    for (int j = 0; j < 4; ++j)
#pragma unroll
      for (int k = 0; k < 4; ++k) acc[i][j][k] = 0.f;

#define STAGE2(kt, b)                                   \
  {                                                     \
    GLD_LDS(gA + (kt) * 32, &s2A[b][(w * 16) * 32]);    \
    GLD_LDS(gB + (kt) * 32, &s2B[b][(w * 16) * 32]);    \
  }

  int frow = lane & 15, kq = lane >> 4;
  int sl = kq ^ ((frow ^ (frow >> 2)) & 3);

#define COMPUTE2(b)                                                     \
  {                                                                     \
    short8 af[2], bfr[4];                                               \
    _Pragma("unroll")                                                   \
    for (int i = 0; i < 2; ++i)                                         \
      af[i] = *(const short8*)&s2A[b][(wr * 32 + i * 16 + frow) * 32 + sl * 8]; \
    _Pragma("unroll")                                                   \
    for (int j = 0; j < 4; ++j)                                         \
      bfr[j] = *(const short8*)&s2B[b][(wc * 64 + j * 16 + frow) * 32 + sl * 8]; \
    _Pragma("unroll")                                                   \
    for (int i = 0; i < 2; ++i)                                         \
      _Pragma("unroll")                                                 \
      for (int j = 0; j < 4; ++j)                                       \
        acc[i][j] = __builtin_amdgcn_mfma_f32_16x16x32_bf16(af[i], bfr[j], acc[i][j], 0, 0, 0); \
  }

  const int nk = FF / 32;
  STAGE2(0, 0);
  __syncthreads();
  int cur = 0;
  for (int kt = 0; kt < nk; ++kt) {
    if (kt + 1 < nk) { STAGE2(kt + 1, cur ^ 1); }
    COMPUTE2(cur);
    __syncthreads();
    cur ^= 1;
  }

  int rq = lane >> 4;
#pragma unroll
  for (int i = 0; i < 2; ++i) {
#pragma unroll
    for (int r = 0; r < 4; ++r) {
      int m = wr * 32 + i * 16 + rq * 4 + r;
      int row = trow * 128 + m;
      if (row < M) {
        int slot = off + row;
        if (SPLIT) {
#pragma unroll
          for (int j = 0; j < 4; ++j) {
            int d = dblk + wc * 64 + j * 16 + frow;
            yb[(size_t)slot * DIM + d] = f2bf(acc[i][j][r]);
          }
        } else {
          int tk = pair_tok[slot];
          float p = pair_p[slot];
#pragma unroll
          for (int j = 0; j < 4; ++j) {
            int d = dblk + wc * 64 + j * 16 + frow;
            atomicAdd(&out[(size_t)tk * DIM + d], (acc[i][j][r] + b2g[e * DIM + d]) * p);
          }
        }
      }
    }
  }
}

// ---------------- combine: out[tok] = sum_k p_k * (y_k + b2[e_k]) ----------------
__global__ __launch_bounds__(256) void combine_kernel(const u16* __restrict__ yb, const float* __restrict__ b2,
                                                      const int* __restrict__ inv_slot, const int* __restrict__ tk_e,
                                                      const float* __restrict__ tk_p, float* __restrict__ out) {
  int tok = blockIdx.x;
  int d4 = threadIdx.x;             // 256 threads x 4 floats = 1024 = DIM
  int i0 = tok * 2, i1 = i0 + 1;
  int s0 = inv_slot[i0], s1 = inv_slot[i1];
  int e0 = tk_e[i0],     e1 = tk_e[i1];
  float p0 = tk_p[i0],   p1 = tk_p[i1];
  uint2 ya = *(const uint2*)(yb + (size_t)s0 * DIM + d4 * 4);
  uint2 yc = *(const uint2*)(yb + (size_t)s1 * DIM + d4 * 4);
  float4 ba = *(const float4*)(b2 + (size_t)e0 * DIM + d4 * 4);
  float4 bb = *(const float4*)(b2 + (size_t)e1 * DIM + d4 * 4);
  float4 r;
  r.x = p0 * (bf2f((u16)(ya.x & 0xffff)) + ba.x) + p1 * (bf2f((u16)(yc.x & 0xffff)) + bb.x);
  r.y = p0 * (bf2f((u16)(ya.x >> 16))   + ba.y) + p1 * (bf2f((u16)(yc.x >> 16))   + bb.y);
  r.z = p0 * (bf2f((u16)(ya.y & 0xffff)) + ba.z) + p1 * (bf2f((u16)(yc.y & 0xffff)) + bb.z);
  r.w = p0 * (bf2f((u16)(ya.y >> 16))   + ba.w) + p1 * (bf2f((u16)(yc.y >> 16))   + bb.w);
  *(float4*)(out + (size_t)tok * DIM + d4 * 4) = r;
}

extern "C" void kernel_launch(void* const* d_in, const int* in_sizes, int n_in,
                              void* d_out, int out_size, void* d_ws, size_t ws_size,
                              hipStream_t stream) {
  const float* x  = (const float*)d_in[0];
  const float* gw = (const float*)d_in[1];
  const float* w1 = (const float*)d_in[2];
  const float* b1 = (const float*)d_in[3];
  const float* w2 = (const float*)d_in[4];
  const float* b2 = (const float*)d_in[5];
  float* out = (float*)d_out;

  char* ws = (char*)d_ws;
  size_t o = 0;
  auto alloc = [&](size_t bytes) { void* p = ws + o; o += (bytes + 255) & ~(size_t)255; return p; };
  u16*   xb       = (u16*)alloc((size_t)NTOK * DIM * 2);
  u16*   w1b      = (u16*)alloc((size_t)NE * FF * DIM * 2);
  u16*   w2b      = (u16*)alloc((size_t)NE * DIM * FF * 2);
  u16*   hbuf     = (u16*)alloc((size_t)NPAIR * FF * 2);
  int*   tk_e     = (int*)alloc((size_t)NPAIR * 4);
  float* tk_p     = (float*)alloc((size_t)NPAIR * 4);
  int*   pair_tok = (int*)alloc((size_t)NPAIR * 4);
  float* pair_p   = (float*)alloc((size_t)NPAIR * 4);
  int*   inv_slot = (int*)alloc((size_t)NPAIR * 4);
  int*   pos_buf  = (int*)alloc((size_t)NPAIR * 4);
  int*   bbase    = (int*)alloc((size_t)(NPAIR / 256) * NE * 4);
  int*   counts   = (int*)alloc(NE * 4);
  int*   offsets  = (int*)alloc(NE * 4);
  if (o > ws_size) return;
  u16* yb = (u16*)(ws + o);
  bool split = (o + (size_t)NPAIR * DIM * 2) <= ws_size;   // 16MB extra for y buffer

  hipMemsetAsync(counts, 0, NE * 4, stream);
  if (!split) hipMemsetAsync(out, 0, (size_t)NTOK * DIM * 4, stream);

  gate_kernel  <<<NTOK / 4, 256, 0, stream>>>(x, gw, xb, tk_e, tk_p);
  route_count_kernel<<<NPAIR / 256, 256, 0, stream>>>(tk_e, counts, bbase, pos_buf);
  route_offsets_kernel<<<1, 64, 0, stream>>>(counts, offsets);
  scatter_kernel<<<NPAIR / 256, 256, 0, stream>>>(tk_e, tk_p, offsets, bbase, pos_buf,
                                                  pair_tok, pair_p, inv_slot);
  cvt_w1_kernel<<<NE * FF * DIM / 4 / 256, 256, 0, stream>>>(w1, w1b);
  // gemm1 grid: 8192 GEMM blocks + 32768 cvt_w2 backfill blocks
  gemm1_kernel<<<NE * 32 * 32 + NE * DIM * FF / 4 / 256, 256, 0, stream>>>(
      xb, w1b, b1, pair_tok, offsets, counts, hbuf, w2, w2b);
  if (split) {
    gemm2_kernel<true><<<NE * 32 * 8, 512, 0, stream>>>(hbuf, w2b, b2, pair_tok, pair_p, offsets, counts, yb, out);
    combine_kernel<<<NTOK, 256, 0, stream>>>(yb, b2, inv_slot, tk_e, tk_p, out);
  } else {
    gemm2_kernel<false><<<NE * 32 * 8, 512, 0, stream>>>(hbuf, w2b, b2, pair_tok, pair_p, offsets, counts, yb, out);
  }
}

// Round 17
// 335.528 us; speedup vs baseline: 1.0784x; 1.0190x over previous
//
#include <hip/hip_runtime.h>
#include <hip/hip_bf16.h>
#include <stdint.h>

#define NTOK 4096      // B*S
#define DIM  1024      // D
#define FF   4096      // F
#define NE   8         // experts
#define NPAIR (NTOK*2) // top-2

using short8 = __attribute__((ext_vector_type(8))) short;
using f32x4  = __attribute__((ext_vector_type(4))) float;
typedef unsigned short u16;
typedef unsigned int   u32;

#define GLD_LDS(gp, lp) \
  __builtin_amdgcn_global_load_lds((const __attribute__((address_space(1))) void*)(gp), \
                                   (__attribute__((address_space(3))) void*)(lp), 16, 0, 0)

__device__ __forceinline__ u16 f2bf(float f) {
  union { float f; u32 u; } v; v.f = f;
  u32 r = (v.u + 0x7fffu + ((v.u >> 16) & 1u)) >> 16;
  return (u16)r;
}
__device__ __forceinline__ float bf2f(u16 u) {
  union { u32 u; float f; } v; v.u = (u32)u << 16; return v.f;
}
__device__ __forceinline__ u32 pack2(float lo, float hi) {
  return (u32)f2bf(lo) | ((u32)f2bf(hi) << 16);
}
// exact rewrite of tanh-gelu: 0.5x(1+tanh(z)) == x * sigmoid(2z)
__device__ __forceinline__ float gelu_fast(float x) {
  float t = x * (-1.5957691216057308f - 0.07135481627822202f * x * x); // -2z
  return x / (1.0f + __expf(t));
}

// ---------------- gating (fused with x -> bf16 cast) + cvt_w1 backfill ----------------
// Blocks [0, 1024): gate. Blocks [1024, 33792): cvt_w1 [F][E][D] -> [E][F][D] (pure BW,
// no dependence on gate; w1b consumed by gemm1 after kernel-boundary sync).
__global__ __launch_bounds__(256) void gate_kernel(const float* __restrict__ x, const float* __restrict__ gw,
                                                   u16* __restrict__ xb,
                                                   int* __restrict__ tk_e, float* __restrict__ tk_p,
                                                   const float* __restrict__ w1, u16* __restrict__ w1b) {
  if (blockIdx.x >= NTOK / 4) {
    // ---- cvt_w1 body ----
    size_t i4 = (size_t)(blockIdx.x - NTOK / 4) * 256 + threadIdx.x;
    int d4 = (int)(i4 & (DIM/4 - 1));
    size_t t = i4 >> 8;
    int f = (int)(t & (FF - 1));
    int e = (int)(t >> 12);
    float4 v = *(const float4*)(w1 + ((size_t)f * NE + e) * DIM + (size_t)d4 * 4);
    *(uint2*)(w1b + ((size_t)e * FF + f) * DIM + (size_t)d4 * 4) =
        make_uint2(pack2(v.x, v.y), pack2(v.z, v.w));
    return;
  }

  int tok  = blockIdx.x * 4 + (threadIdx.x >> 6);
  int lane = threadIdx.x & 63;
  const float* xr = x + (size_t)tok * DIM;
  u16* xw = xb + (size_t)tok * DIM;
  float acc[NE];
#pragma unroll
  for (int e = 0; e < NE; ++e) acc[e] = 0.f;
#pragma unroll
  for (int it = 0; it < 4; ++it) {
    int d = it * 256 + lane * 4;
    float4 xv = *(const float4*)(xr + d);
    *(uint2*)(xw + d) = make_uint2(pack2(xv.x, xv.y), pack2(xv.z, xv.w));
#pragma unroll
    for (int e = 0; e < NE; ++e) {
      float4 gv = *(const float4*)(gw + (size_t)e * DIM + d);
      acc[e] += xv.x * gv.x + xv.y * gv.y + xv.z * gv.z + xv.w * gv.w;
    }
  }
#pragma unroll
  for (int e = 0; e < NE; ++e)
#pragma unroll
    for (int off = 32; off; off >>= 1) acc[e] += __shfl_xor(acc[e], off);

  if (lane == 0) {
    float mx = acc[0];
#pragma unroll
    for (int e = 1; e < NE; ++e) mx = fmaxf(mx, acc[e]);
    float pr[NE]; float s = 0.f;
#pragma unroll
    for (int e = 0; e < NE; ++e) { pr[e] = __expf(acc[e] - mx); s += pr[e]; }
    float inv = 1.f / s;
    int e0 = 0; float p0 = pr[0];
#pragma unroll
    for (int e = 1; e < NE; ++e) if (pr[e] > p0) { p0 = pr[e]; e0 = e; }
    int e1 = (e0 == 0) ? 1 : 0; float p1 = pr[e1];
#pragma unroll
    for (int e = 0; e < NE; ++e) if (e != e0 && pr[e] > p1) { p1 = pr[e]; e1 = e; }
    tk_e[tok * 2]     = e0; tk_p[tok * 2]     = p0 * inv;
    tk_e[tok * 2 + 1] = e1; tk_p[tok * 2 + 1] = p1 * inv;
  }
}

// ---------------- routing: LDS histogram, 8 global atomics per block (G12) ----------------
__global__ __launch_bounds__(256) void route_count_kernel(const int* __restrict__ tk_e,
                                                          int* __restrict__ counts,
                                                          int* __restrict__ bbase,
                                                          int* __restrict__ pos_buf) {
  __shared__ int hist[NE];
  if (threadIdx.x < NE) hist[threadIdx.x] = 0;
  __syncthreads();
  int i = blockIdx.x * 256 + threadIdx.x;
  int e = tk_e[i];
  pos_buf[i] = atomicAdd(&hist[e], 1);
  __syncthreads();
  if (threadIdx.x < NE) {
    int c = hist[threadIdx.x];
    bbase[blockIdx.x * NE + threadIdx.x] = atomicAdd(&counts[threadIdx.x], c);
  }
}

__global__ void route_offsets_kernel(const int* __restrict__ counts, int* __restrict__ offsets) {
  if (threadIdx.x == 0) { int s = 0; for (int e = 0; e < NE; ++e) { offsets[e] = s; s += counts[e]; } }
}

__global__ __launch_bounds__(256) void scatter_kernel(const int* __restrict__ tk_e, const float* __restrict__ tk_p,
                                                      const int* __restrict__ offsets,
                                                      const int* __restrict__ bbase, const int* __restrict__ pos_buf,
                                                      int* __restrict__ pair_tok, float* __restrict__ pair_p,
                                                      int* __restrict__ inv_slot) {
  int i = blockIdx.x * 256 + threadIdx.x;
  int e = tk_e[i];
  int slot = offsets[e] + bbase[blockIdx.x * NE + e] + pos_buf[i];
  pair_tok[slot] = i >> 1;
  pair_p[slot]   = tk_p[i];
  inv_slot[i]    = slot;
}

// ---------------- grouped GEMM1 + fused cvt_w2 backfill (R16-proven) ----------------
__global__ __launch_bounds__(256, 4) void gemm1_kernel(const u16* __restrict__ xb, const u16* __restrict__ w1b,
                                                       const float* __restrict__ b1g,
                                                       const int* __restrict__ pair_tok,
                                                       const int* __restrict__ offsets, const int* __restrict__ counts,
                                                       u16* __restrict__ h,
                                                       const float* __restrict__ w2, u16* __restrict__ w2b) {
  if (blockIdx.x >= NE * 32 * 32) {
    // ---- cvt_w2 body: [D][E][F] -> [E][D][F] ----
    size_t i4 = (size_t)(blockIdx.x - NE * 32 * 32) * 256 + threadIdx.x;
    int f4 = (int)(i4 & (FF/4 - 1));
    size_t t = i4 >> 10;
    int d = (int)(t & (DIM - 1));
    int e = (int)(t >> 10);
    float4 v = *(const float4*)(w2 + ((size_t)d * NE + e) * FF + (size_t)f4 * 4);
    *(uint2*)(w2b + ((size_t)e * DIM + d) * FF + (size_t)f4 * 4) =
        make_uint2(pack2(v.x, v.y), pack2(v.z, v.w));
    return;
  }

  int lin = blockIdx.x;           // lin = trow*256 + e*32 + fblk_i  (R7 flat)
  int trow = lin >> 8;
  int rem = lin & 255;
  int e = rem >> 5;
  int fblk = (rem & 31) << 7;
  int M = counts[e];
  if (trow * 128 >= M) return;
  int off = offsets[e];

  __shared__ __align__(16) u16 sA[2][128 * 32];
  __shared__ __align__(16) u16 sB[2][128 * 32];

  int tid = threadIdx.x, lane = tid & 63, w = tid >> 6;
  int wr = w >> 1, wc = w & 1;

  int lr = lane >> 2;
  int cs = (lane & 3) ^ (((lane >> 2) ^ (lane >> 4)) & 3);
  const u16* gA[2]; const u16* gB[2];
#pragma unroll
  for (int cc = 0; cc < 2; ++cc) {
    int lrow = cc * 64 + w * 16 + lr;
    int arow = trow * 128 + lrow;
    int tok = pair_tok[off + (arow < M ? arow : M - 1)];
    gA[cc] = xb + (size_t)tok * DIM + cs * 8;
    gB[cc] = w1b + ((size_t)e * FF + fblk + lrow) * DIM + cs * 8;
  }

  f32x4 acc[4][4];
#pragma unroll
  for (int i = 0; i < 4; ++i)
#pragma unroll
    for (int j = 0; j < 4; ++j)
#pragma unroll
      for (int k = 0; k < 4; ++k) acc[i][j][k] = 0.f;

#define STAGE1(kt, b)                                                   \
  _Pragma("unroll")                                                     \
  for (int cc = 0; cc < 2; ++cc) {                                      \
    GLD_LDS(gA[cc] + (kt) * 32, &sA[b][(cc * 64 + w * 16) * 32]);       \
    GLD_LDS(gB[cc] + (kt) * 32, &sB[b][(cc * 64 + w * 16) * 32]);       \
  }

  int frow = lane & 15, kq = lane >> 4;
  int sl = kq ^ ((frow ^ (frow >> 2)) & 3);

#define COMPUTE1(b)                                                     \
  {                                                                     \
    short8 af[4], bfr[4];                                               \
    _Pragma("unroll")                                                   \
    for (int i = 0; i < 4; ++i) {                                       \
      af[i]  = *(const short8*)&sA[b][(wr * 64 + i * 16 + frow) * 32 + sl * 8]; \
      bfr[i] = *(const short8*)&sB[b][(wc * 64 + i * 16 + frow) * 32 + sl * 8]; \
    }                                                                   \
    _Pragma("unroll")                                                   \
    for (int i = 0; i < 4; ++i)                                         \
      _Pragma("unroll")                                                 \
      for (int j = 0; j < 4; ++j)                                       \
        acc[i][j] = __builtin_amdgcn_mfma_f32_16x16x32_bf16(af[i], bfr[j], acc[i][j], 0, 0, 0); \
  }

  const int nk = DIM / 32;
  STAGE1(0, 0);
  __syncthreads();
  int cur = 0;
  for (int kt = 0; kt < nk; ++kt) {
    if (kt + 1 < nk) { STAGE1(kt + 1, cur ^ 1); }
    COMPUTE1(cur);
    __syncthreads();
    cur ^= 1;
  }

  float b1v[4];
#pragma unroll
  for (int j = 0; j < 4; ++j)
    b1v[j] = b1g[e * FF + fblk + wc * 64 + j * 16 + frow];

  int rq = lane >> 4;
#pragma unroll
  for (int i = 0; i < 4; ++i) {
#pragma unroll
    for (int r = 0; r < 4; ++r) {
      int m = wr * 64 + i * 16 + rq * 4 + r;
      int row = trow * 128 + m;
      if (row < M) {
        size_t hbase = (size_t)(off + row) * FF;
#pragma unroll
        for (int j = 0; j < 4; ++j) {
          int f = fblk + wc * 64 + j * 16 + frow;
          h[hbase + f] = f2bf(gelu_fast(acc[i][j][r] + b1v[j]));
        }
      }
    }
  }
}

// ---------------- grouped GEMM2 (R7-proven, 512 thr, 8 waves, flat mapping) ----------------
template<bool SPLIT>
__global__ __launch_bounds__(512, 4) void gemm2_kernel(const u16* __restrict__ h, const u16* __restrict__ w2b,
                                                       const float* __restrict__ b2g,
                                                       const int* __restrict__ pair_tok, const float* __restrict__ pair_p,
                                                       const int* __restrict__ offsets, const int* __restrict__ counts,
                                                       u16* __restrict__ yb, float* __restrict__ out) {
  int lin = blockIdx.x;           // lin = trow*64 + e*8 + dblk_i  (R7 flat)
  int trow = lin >> 6;
  int rem = lin & 63;
  int e = rem >> 3;
  int dblk = (rem & 7) << 7;
  int M = counts[e];
  if (trow * 128 >= M) return;
  int off = offsets[e];

  __shared__ __align__(16) u16 s2A[2][128 * 32];
  __shared__ __align__(16) u16 s2B[2][128 * 32];

  int tid = threadIdx.x, lane = tid & 63, w = tid >> 6;   // w in 0..7
  int wr = w >> 1, wc = w & 1;                            // 4x2 wave grid, wave tile 32x64

  int lr = lane >> 2;
  int cs = (lane & 3) ^ (((lane >> 2) ^ (lane >> 4)) & 3);
  int lrow = w * 16 + lr;                                 // 0..127
  int arow = trow * 128 + lrow;
  int slot_a = off + (arow < M ? arow : M - 1);           // h is SLOT-indexed
  const u16* gA = h + (size_t)slot_a * FF + cs * 8;
  const u16* gB = w2b + ((size_t)e * DIM + dblk + lrow) * FF + cs * 8;

  f32x4 acc[2][4];
#pragma unroll
  for (int i = 0; i < 2; ++i)
#pragma unroll
    for (int j = 0; j < 4; ++j)
#pragma unroll
      for (int k = 0; k < 4; ++k) acc[i][j][k] = 0.f;

#define STAGE2(kt, b)                                   \
  {                                                     \
    GLD_LDS(gA + (kt) * 32, &s2A[b][(w * 16) * 32]);    \
    GLD_LDS(gB + (kt) * 32, &s2B[b][(w * 16) * 32]);    \
  }

  int frow = lane & 15, kq = lane >> 4;
  int sl = kq ^ ((frow ^ (frow >> 2)) & 3);

#define COMPUTE2(b)                                                     \
  {                                                                     \
    short8 af[2], bfr[4];                                               \
    _Pragma("unroll")                                                   \
    for (int i = 0; i < 2; ++i)                                         \
      af[i] = *(const short8*)&s2A[b][(wr * 32 + i * 16 + frow) * 32 + sl * 8]; \
    _Pragma("unroll")                                                   \
    for (int j = 0; j < 4; ++j)                                         \
      bfr[j] = *(const short8*)&s2B[b][(wc * 64 + j * 16 + frow) * 32 + sl * 8]; \
    _Pragma("unroll")                                                   \
    for (int i = 0; i < 2; ++i)                                         \
      _Pragma("unroll")                                                 \
      for (int j = 0; j < 4; ++j)                                       \
        acc[i][j] = __builtin_amdgcn_mfma_f32_16x16x32_bf16(af[i], bfr[j], acc[i][j], 0, 0, 0); \
  }

  const int nk = FF / 32;
  STAGE2(0, 0);
  __syncthreads();
  int cur = 0;
  for (int kt = 0; kt < nk; ++kt) {
    if (kt + 1 < nk) { STAGE2(kt + 1, cur ^ 1); }
    COMPUTE2(cur);
    __syncthreads();
    cur ^= 1;
  }

  int rq = lane >> 4;
#pragma unroll
  for (int i = 0; i < 2; ++i) {
#pragma unroll
    for (int r = 0; r < 4; ++r) {
      int m = wr * 32 + i * 16 + rq * 4 + r;
      int row = trow * 128 + m;
      if (row < M) {
        int slot = off + row;
        if (SPLIT) {
#pragma unroll
          for (int j = 0; j < 4; ++j) {
            int d = dblk + wc * 64 + j * 16 + frow;
            yb[(size_t)slot * DIM + d] = f2bf(acc[i][j][r]);
          }
        } else {
          int tk = pair_tok[slot];
          float p = pair_p[slot];
#pragma unroll
          for (int j = 0; j < 4; ++j) {
            int d = dblk + wc * 64 + j * 16 + frow;
            atomicAdd(&out[(size_t)tk * DIM + d], (acc[i][j][r] + b2g[e * DIM + d]) * p);
          }
        }
      }
    }
  }
}

// ---------------- combine: out[tok] = sum_k p_k * (y_k + b2[e_k]) ----------------
__global__ __launch_bounds__(256) void combine_kernel(const u16* __restrict__ yb, const float* __restrict__ b2,
                                                      const int* __restrict__ inv_slot, const int* __restrict__ tk_e,
                                                      const float* __restrict__ tk_p, float* __restrict__ out) {
  int tok = blockIdx.x;
  int d4 = threadIdx.x;             // 256 threads x 4 floats = 1024 = DIM
  int i0 = tok * 2, i1 = i0 + 1;
  int s0 = inv_slot[i0], s1 = inv_slot[i1];
  int e0 = tk_e[i0],     e1 = tk_e[i1];
  float p0 = tk_p[i0],   p1 = tk_p[i1];
  uint2 ya = *(const uint2*)(yb + (size_t)s0 * DIM + d4 * 4);
  uint2 yc = *(const uint2*)(yb + (size_t)s1 * DIM + d4 * 4);
  float4 ba = *(const float4*)(b2 + (size_t)e0 * DIM + d4 * 4);
  float4 bb = *(const float4*)(b2 + (size_t)e1 * DIM + d4 * 4);
  float4 r;
  r.x = p0 * (bf2f((u16)(ya.x & 0xffff)) + ba.x) + p1 * (bf2f((u16)(yc.x & 0xffff)) + bb.x);
  r.y = p0 * (bf2f((u16)(ya.x >> 16))   + ba.y) + p1 * (bf2f((u16)(yc.x >> 16))   + bb.y);
  r.z = p0 * (bf2f((u16)(ya.y & 0xffff)) + ba.z) + p1 * (bf2f((u16)(yc.y & 0xffff)) + bb.z);
  r.w = p0 * (bf2f((u16)(ya.y >> 16))   + ba.w) + p1 * (bf2f((u16)(yc.y >> 16))   + bb.w);
  *(float4*)(out + (size_t)tok * DIM + d4 * 4) = r;
}

extern "C" void kernel_launch(void* const* d_in, const int* in_sizes, int n_in,
                              void* d_out, int out_size, void* d_ws, size_t ws_size,
                              hipStream_t stream) {
  const float* x  = (const float*)d_in[0];
  const float* gw = (const float*)d_in[1];
  const float* w1 = (const float*)d_in[2];
  const float* b1 = (const float*)d_in[3];
  const float* w2 = (const float*)d_in[4];
  const float* b2 = (const float*)d_in[5];
  float* out = (float*)d_out;

  char* ws = (char*)d_ws;
  size_t o = 0;
  auto alloc = [&](size_t bytes) { void* p = ws + o; o += (bytes + 255) & ~(size_t)255; return p; };
  u16*   xb       = (u16*)alloc((size_t)NTOK * DIM * 2);
  u16*   w1b      = (u16*)alloc((size_t)NE * FF * DIM * 2);
  u16*   w2b      = (u16*)alloc((size_t)NE * DIM * FF * 2);
  u16*   hbuf     = (u16*)alloc((size_t)NPAIR * FF * 2);
  int*   tk_e     = (int*)alloc((size_t)NPAIR * 4);
  float* tk_p     = (float*)alloc((size_t)NPAIR * 4);
  int*   pair_tok = (int*)alloc((size_t)NPAIR * 4);
  float* pair_p   = (float*)alloc((size_t)NPAIR * 4);
  int*   inv_slot = (int*)alloc((size_t)NPAIR * 4);
  int*   pos_buf  = (int*)alloc((size_t)NPAIR * 4);
  int*   bbase    = (int*)alloc((size_t)(NPAIR / 256) * NE * 4);
  int*   counts   = (int*)alloc(NE * 4);
  int*   offsets  = (int*)alloc(NE * 4);
  if (o > ws_size) return;
  u16* yb = (u16*)(ws + o);
  bool split = (o + (size_t)NPAIR * DIM * 2) <= ws_size;   // 16MB extra for y buffer

  hipMemsetAsync(counts, 0, NE * 4, stream);
  if (!split) hipMemsetAsync(out, 0, (size_t)NTOK * DIM * 4, stream);

  // gate grid: 1024 gate blocks + 32768 cvt_w1 backfill blocks
  gate_kernel<<<NTOK / 4 + NE * FF * DIM / 4 / 256, 256, 0, stream>>>(
      x, gw, xb, tk_e, tk_p, w1, w1b);
  route_count_kernel<<<NPAIR / 256, 256, 0, stream>>>(tk_e, counts, bbase, pos_buf);
  route_offsets_kernel<<<1, 64, 0, stream>>>(counts, offsets);
  scatter_kernel<<<NPAIR / 256, 256, 0, stream>>>(tk_e, tk_p, offsets, bbase, pos_buf,
                                                  pair_tok, pair_p, inv_slot);
  // gemm1 grid: 8192 GEMM blocks + 32768 cvt_w2 backfill blocks
  gemm1_kernel<<<NE * 32 * 32 + NE * DIM * FF / 4 / 256, 256, 0, stream>>>(
      xb, w1b, b1, pair_tok, offsets, counts, hbuf, w2, w2b);
  if (split) {
    gemm2_kernel<true><<<NE * 32 * 8, 512, 0, stream>>>(hbuf, w2b, b2, pair_tok, pair_p, offsets, counts, yb, out);
    combine_kernel<<<NTOK, 256, 0, stream>>>(yb, b2, inv_slot, tk_e, tk_p, out);
  } else {
    gemm2_kernel<false><<<NE * 32 * 8, 512, 0, stream>>>(hbuf, w2b, b2, pair_tok, pair_p, offsets, counts, yb, out);
  }
}